// Round 1
// baseline (161.099 us; speedup 1.0000x reference)
//
#include <hip/hip_runtime.h>
#include <math.h>

#define NB 8
#define NA 192
#define ND 128
#define NREL 5
#define NH 128
// fan_in = 6*ND + NREL + ND = 901
// W1 rows: [0:128) ci, [128:256) cj, [256:384) gi, [384:512) gj,
//          [512:640) fi, [640:768) fj, [768:773) rel, [773:901) gc

// ---------------- Kernel 1: P[row][0:128]=Pi, [128:256]=Pj ----------------
// X row = [coord | goal | frontier] (3*128), GEMM [3072 x 384] @ [384 x 256]
__global__ __launch_bounds__(256) void precompute_P(
    const float* __restrict__ coord, const float* __restrict__ goal,
    const float* __restrict__ frontier, const float* __restrict__ W1,
    float* __restrict__ P)
{
    const int ROWS = 16;
    __shared__ float X[ROWS][3 * ND];
    const int r0 = blockIdx.x * ROWS;
    const int tid = threadIdx.x;

    for (int idx = tid; idx < ROWS * 3 * ND; idx += 256) {
        int r = idx / (3 * ND);
        int k = idx % (3 * ND);
        int s = k >> 7, d = k & 127;
        const float* src = (s == 0) ? coord : (s == 1) ? goal : frontier;
        X[r][k] = src[(r0 + r) * ND + d];
    }
    __syncthreads();

    const int c = tid;                 // 0..255 output column (Pi c<128, Pj c>=128)
    const int colLocal = c & 127;
    const int roleOff = (c >> 7) * 128;  // row offset: 0 for i-role, 128 for j-role

    float acc[ROWS];
#pragma unroll
    for (int r = 0; r < ROWS; r++) acc[r] = 0.f;

    for (int k = 0; k < 3 * ND; k += 4) {
        int s = k >> 7, d = k & 127;   // d..d+3 stay inside the same 128-chunk
        const float* wptr = &W1[(256 * s + roleOff + d) * NH + colLocal];
        float w0 = wptr[0 * NH];
        float w1 = wptr[1 * NH];
        float w2 = wptr[2 * NH];
        float w3 = wptr[3 * NH];
#pragma unroll
        for (int r = 0; r < ROWS; r++) {
            float4 x = *(const float4*)&X[r][k];   // wave-uniform broadcast read
            acc[r] += x.x * w0 + x.y * w1 + x.z * w2 + x.w * w3;
        }
    }
#pragma unroll
    for (int r = 0; r < ROWS; r++) P[(r0 + r) * 256 + c] = acc[r];
}

// ---------------- Kernel 2: Gc[b][h] = gc[b] @ W1[773:901] + b1 ----------------
__global__ __launch_bounds__(128) void precompute_Gc(
    const float* __restrict__ gc, const float* __restrict__ W1,
    const float* __restrict__ b1, float* __restrict__ Gc)
{
    const int b = blockIdx.x;
    const int h = threadIdx.x;
    float acc = b1[h];
    for (int d = 0; d < ND; ++d)
        acc += gc[b * ND + d] * W1[(6 * ND + NREL + d) * NH + h];
    Gc[b * NH + h] = acc;
}

// ---------------- Kernel 3: per-(b,i) edge MLP + masked softmax ----------------
__global__ __launch_bounds__(256) void edge_kernel(
    const float* __restrict__ P, const float* __restrict__ Gc,
    const float* __restrict__ W1, const float* __restrict__ W2,
    const float* __restrict__ b2v, const float* __restrict__ rel_feat,
    const int* __restrict__ rule_adj, const float* __restrict__ base_score,
    float* __restrict__ out_w, float* __restrict__ out_s, float* __restrict__ out_l)
{
    const int bi = blockIdx.x;           // b*NA + i
    const int b = bi / NA;

    __shared__ float s_pig[NH];          // Pi + Gc
    __shared__ float s_wrel[NREL * NH];  // W1 rows 768..772
    __shared__ float s_rel[NA * NREL];   // rel_feat row for this (b,i)
    __shared__ float s_learned[NA];

    const int tid = threadIdx.x;
    if (tid < NH) s_pig[tid] = P[bi * 256 + tid] + Gc[b * NH + tid];
    for (int idx = tid; idx < NREL * NH; idx += 256)
        s_wrel[idx] = W1[6 * ND * NH + idx];
    for (int idx = tid; idx < NA * NREL; idx += 256)
        s_rel[idx] = rel_feat[(size_t)bi * NA * NREL + idx];
    __syncthreads();

    const int wave = tid >> 6, lane = tid & 63;
    const int h0 = lane, h1 = lane + 64;
    const float w2_0 = W2[h0], w2_1 = W2[h1];
    const float pig0 = s_pig[h0], pig1 = s_pig[h1];
    float wr0[NREL], wr1[NREL];
#pragma unroll
    for (int r = 0; r < NREL; r++) {
        wr0[r] = s_wrel[r * NH + h0];
        wr1[r] = s_wrel[r * NH + h1];
    }
    const float bb2 = b2v[0];

    for (int j = wave; j < NA; j += 4) {
        float pj0 = P[(b * NA + j) * 256 + 128 + h0];
        float pj1 = P[(b * NA + j) * 256 + 128 + h1];
        float pre0 = pig0 + pj0;
        float pre1 = pig1 + pj1;
#pragma unroll
        for (int r = 0; r < NREL; r++) {
            float rv = s_rel[j * NREL + r];
            pre0 += rv * wr0[r];
            pre1 += rv * wr1[r];
        }
        float v = fmaxf(pre0, 0.f) * w2_0 + fmaxf(pre1, 0.f) * w2_1;
#pragma unroll
        for (int off = 32; off > 0; off >>= 1) v += __shfl_xor(v, off, 64);
        if (lane == 0) s_learned[j] = v + bb2;
    }
    __syncthreads();

    // learned output (unmasked)
    if (tid < NA) out_l[bi * NA + tid] = s_learned[tid];

    // masked softmax + renorm, wave 0 only (3 j's per lane)
    if (wave == 0) {
        float sc[3], e[3], wj[3];
        int adj[3];
        float m = -3.4e38f;
#pragma unroll
        for (int t = 0; t < 3; t++) {
            int j = lane + 64 * t;
            adj[t] = rule_adj[bi * NA + j];
            float s = base_score[bi * NA + j] + s_learned[j];
            sc[t] = adj[t] ? s : -1e9f;
            m = fmaxf(m, sc[t]);
        }
#pragma unroll
        for (int off = 32; off > 0; off >>= 1) m = fmaxf(m, __shfl_xor(m, off, 64));
        float S = 0.f;
#pragma unroll
        for (int t = 0; t < 3; t++) { e[t] = __expf(sc[t] - m); S += e[t]; }
#pragma unroll
        for (int off = 32; off > 0; off >>= 1) S += __shfl_xor(S, off, 64);
        float invS = 1.f / S;
        float sw = 0.f;
#pragma unroll
        for (int t = 0; t < 3; t++) { wj[t] = adj[t] ? e[t] * invS : 0.f; sw += wj[t]; }
#pragma unroll
        for (int off = 32; off > 0; off >>= 1) sw += __shfl_xor(sw, off, 64);
        float inv = 1.f / (sw + 1e-8f);
#pragma unroll
        for (int t = 0; t < 3; t++) {
            int j = lane + 64 * t;
            out_w[bi * NA + j] = wj[t] * inv;
            out_s[bi * NA + j] = sc[t];
        }
    }
}

extern "C" void kernel_launch(void* const* d_in, const int* in_sizes, int n_in,
                              void* d_out, int out_size, void* d_ws, size_t ws_size,
                              hipStream_t stream) {
    const float* coord    = (const float*)d_in[0];
    const float* goal     = (const float*)d_in[1];
    const float* frontier = (const float*)d_in[2];
    const float* rel_feat = (const float*)d_in[3];
    const int*   rule_adj = (const int*)d_in[4];
    const float* base_sc  = (const float*)d_in[5];
    const float* gctx     = (const float*)d_in[6];
    const float* W1       = (const float*)d_in[7];
    const float* b1       = (const float*)d_in[8];
    const float* W2       = (const float*)d_in[9];
    const float* b2       = (const float*)d_in[10];

    float* P  = (float*)d_ws;                          // 3072*256 floats = 3 MiB
    float* Gc = P + NB * NA * 256;                     // 8*128 floats

    float* out_w = (float*)d_out;
    float* out_s = out_w + NB * NA * NA;
    float* out_l = out_s + NB * NA * NA;

    precompute_P<<<(NB * NA) / 16, 256, 0, stream>>>(coord, goal, frontier, W1, P);
    precompute_Gc<<<NB, 128, 0, stream>>>(gctx, W1, b1, Gc);
    edge_kernel<<<NB * NA, 256, 0, stream>>>(P, Gc, W1, W2, b2, rel_feat,
                                             rule_adj, base_sc, out_w, out_s, out_l);
}

// Round 2
// 122.721 us; speedup vs baseline: 1.3127x; 1.3127x over previous
//
#include <hip/hip_runtime.h>
#include <math.h>

#define NB 8
#define NA 192
#define ND 128
#define NREL 5
#define NH 128
#define ROWS 6
#define NPBLK ((NB * NA) / ROWS)   // 512 P-blocks, then 8 Gc blocks
// fan_in = 6*ND + NREL + ND = 901
// W1 rows: [0:128) ci, [128:256) cj, [256:384) gi, [384:512) gj,
//          [512:640) fi, [640:768) fj, [768:773) rel, [773:901) gc

// ---------------- Kernel 1: Pi[row][h], PjT[b][h][a], Gc[b][h] ----------------
__global__ __launch_bounds__(256) void precompute_P(
    const float* __restrict__ coord, const float* __restrict__ goal,
    const float* __restrict__ frontier, const float* __restrict__ gctx,
    const float* __restrict__ W1, const float* __restrict__ b1,
    float* __restrict__ Pi, float* __restrict__ PjT, float* __restrict__ Gc)
{
    const int blk = blockIdx.x;
    const int tid = threadIdx.x;

    if (blk >= NPBLK) {
        // ---- Gc block: one per b, 256 threads = (h, half-of-d) ----
        __shared__ float red[256];
        const int b = blk - NPBLK;
        const int h = tid & 127, part = tid >> 7;
        const float* g = gctx + b * ND + part * 64;
        const float* w = W1 + (size_t)(6 * ND + NREL + part * 64) * NH + h;
        float acc = 0.f;
#pragma unroll 8
        for (int d = 0; d < 64; ++d) acc += g[d] * w[d * NH];
        red[tid] = acc;
        __syncthreads();
        if (part == 0) Gc[b * NH + h] = red[h] + red[h + 128] + b1[h];
        return;
    }

    // ---- P block: 6 rows x 256 output columns ----
    __shared__ __align__(16) float X[ROWS][3 * ND];
    const int r0 = blk * ROWS;

    for (int idx = tid; idx < ROWS * 3 * ND; idx += 256) {
        int r = idx / (3 * ND);
        int k = idx % (3 * ND);
        int s = k >> 7, d = k & 127;
        const float* src = (s == 0) ? coord : (s == 1) ? goal : frontier;
        X[r][k] = src[(r0 + r) * ND + d];
    }
    __syncthreads();

    const int colLocal = tid & 127;
    const int role = tid >> 7;            // 0 = i-role, 1 = j-role
    const int roleOff = role * 128;

    float acc[ROWS];
#pragma unroll
    for (int r = 0; r < ROWS; r++) acc[r] = 0.f;

    for (int s = 0; s < 3; ++s) {
        const float* wb = W1 + (size_t)(256 * s + roleOff) * NH + colLocal;
#pragma unroll 2
        for (int d = 0; d < ND; d += 4) {
            float w0 = wb[(d + 0) * NH];
            float w1 = wb[(d + 1) * NH];
            float w2 = wb[(d + 2) * NH];
            float w3 = wb[(d + 3) * NH];
#pragma unroll
            for (int r = 0; r < ROWS; r++) {
                float4 x = *(const float4*)&X[r][s * ND + d];
                acc[r] += x.x * w0 + x.y * w1 + x.z * w2 + x.w * w3;
            }
        }
    }

#pragma unroll
    for (int r = 0; r < ROWS; r++) {
        int row = r0 + r;
        if (role == 0) {
            Pi[(size_t)row * NH + colLocal] = acc[r];
        } else {
            int b = row / NA, a = row % NA;
            PjT[((size_t)b * NH + colLocal) * NA + a] = acc[r];
        }
    }
}

// ---------------- Kernel 2: per-(b,i) edge MLP + masked softmax ----------------
// 192 threads, lane = j. PjT loads coalesced; uniforms via LDS broadcast b128.
__global__ __launch_bounds__(192) void edge_kernel(
    const float* __restrict__ Pi, const float* __restrict__ PjT,
    const float* __restrict__ Gc, const float* __restrict__ W1,
    const float* __restrict__ W2, const float* __restrict__ b2v,
    const float* __restrict__ rel_feat, const int* __restrict__ rule_adj,
    const float* __restrict__ base_score,
    float* __restrict__ out_w, float* __restrict__ out_s, float* __restrict__ out_l)
{
    const int bi = blockIdx.x;           // b*NA + i
    const int b = bi / NA;
    const int tid = threadIdx.x;         // = j, 0..191

    __shared__ float4 su1[NH];           // {pig, wrel0, wrel1, wrel2}
    __shared__ float4 su2[NH];           // {wrel3, wrel4, w2, 0}
    __shared__ float redA[3], redB[3], redC[3];

    if (tid < NH) {
        float pig = Pi[(size_t)bi * NH + tid] + Gc[b * NH + tid];
        const float* wr = W1 + (size_t)(6 * ND) * NH + tid;
        su1[tid] = make_float4(pig, wr[0 * NH], wr[1 * NH], wr[2 * NH]);
        su2[tid] = make_float4(wr[3 * NH], wr[4 * NH], W2[tid], 0.f);
    }

    float rel[NREL];
    const float* rf = rel_feat + ((size_t)bi * NA + tid) * NREL;
#pragma unroll
    for (int r = 0; r < NREL; r++) rel[r] = rf[r];

    __syncthreads();

    const float* pj = PjT + (size_t)b * NH * NA + tid;
    float acc = 0.f;
#pragma unroll 4
    for (int h = 0; h < NH; ++h) {
        float p = pj[h * NA];
        float4 a = su1[h];
        float4 c = su2[h];
        float pre = a.x + p;
        pre += rel[0] * a.y;
        pre += rel[1] * a.z;
        pre += rel[2] * a.w;
        pre += rel[3] * c.x;
        pre += rel[4] * c.y;
        acc += fmaxf(pre, 0.f) * c.z;
    }
    float learned = acc + b2v[0];
    out_l[(size_t)bi * NA + tid] = learned;

    const int adj = rule_adj[(size_t)bi * NA + tid];
    const float sc = adj ? (base_score[(size_t)bi * NA + tid] + learned) : -1e9f;
    out_s[(size_t)bi * NA + tid] = sc;

    const int wave = tid >> 6, lane = tid & 63;

    // max over 192 lanes
    float m = sc;
#pragma unroll
    for (int off = 32; off > 0; off >>= 1) m = fmaxf(m, __shfl_xor(m, off, 64));
    if (lane == 0) redA[wave] = m;
    __syncthreads();
    m = fmaxf(fmaxf(redA[0], redA[1]), redA[2]);

    // sum of exp
    float e = __expf(sc - m);
    float S = e;
#pragma unroll
    for (int off = 32; off > 0; off >>= 1) S += __shfl_xor(S, off, 64);
    if (lane == 0) redB[wave] = S;
    __syncthreads();
    S = redB[0] + redB[1] + redB[2];

    // masked renorm
    float wj = adj ? e * (1.f / S) : 0.f;
    float sw = wj;
#pragma unroll
    for (int off = 32; off > 0; off >>= 1) sw += __shfl_xor(sw, off, 64);
    if (lane == 0) redC[wave] = sw;
    __syncthreads();
    sw = redC[0] + redC[1] + redC[2];

    out_w[(size_t)bi * NA + tid] = wj * (1.f / (sw + 1e-8f));
}

extern "C" void kernel_launch(void* const* d_in, const int* in_sizes, int n_in,
                              void* d_out, int out_size, void* d_ws, size_t ws_size,
                              hipStream_t stream) {
    const float* coord    = (const float*)d_in[0];
    const float* goal     = (const float*)d_in[1];
    const float* frontier = (const float*)d_in[2];
    const float* rel_feat = (const float*)d_in[3];
    const int*   rule_adj = (const int*)d_in[4];
    const float* base_sc  = (const float*)d_in[5];
    const float* gctx     = (const float*)d_in[6];
    const float* W1       = (const float*)d_in[7];
    const float* b1       = (const float*)d_in[8];
    const float* W2       = (const float*)d_in[9];
    const float* b2       = (const float*)d_in[10];

    float* Pi  = (float*)d_ws;                 // 8*192*128 = 196608 floats
    float* PjT = Pi + NB * NA * NH;            // 8*128*192 = 196608 floats
    float* Gc  = PjT + NB * NH * NA;           // 8*128

    float* out_w = (float*)d_out;
    float* out_s = out_w + NB * NA * NA;
    float* out_l = out_s + NB * NA * NA;

    precompute_P<<<NPBLK + NB, 256, 0, stream>>>(coord, goal, frontier, gctx,
                                                 W1, b1, Pi, PjT, Gc);
    edge_kernel<<<NB * NA, 192, 0, stream>>>(Pi, PjT, Gc, W1, W2, b2, rel_feat,
                                             rule_adj, base_sc, out_w, out_s, out_l);
}

// Round 3
// 116.805 us; speedup vs baseline: 1.3792x; 1.0506x over previous
//
#include <hip/hip_runtime.h>
#include <math.h>

#define NB 8
#define NA 192
#define ND 128
#define NREL 5
#define NH 128
#define ROWS 6
#define NROWBLK ((NB * NA) / ROWS)      // 256 row-blocks
#define NPBLK (NROWBLK * 2)             // x2 k-halves = 512... (see grid: rb = blk>>1)
// fan_in = 6*ND + NREL + ND = 901
// W1 rows: [0:128) ci, [128:256) cj, [256:384) gi, [384:512) gj,
//          [512:640) fi, [640:768) fj, [768:773) rel, [773:901) gc

// ---------------- Kernel 1: k-split partial projections + Gc ----------------
// blk < 2*NROWBLK: rb = blk>>1 (6 rows), kh = blk&1 (k-half of 384).
//   role 0 (tid<128): PiP[kh][row][h] (+= half of Pi)
//   role 1          : PjTP[kh][b][h][a]
// tail blocks: Gc[b][h] = gctx[b] @ W1[773:901] + b1
__global__ __launch_bounds__(256, 4) void precompute_P(
    const float* __restrict__ coord, const float* __restrict__ goal,
    const float* __restrict__ frontier, const float* __restrict__ gctx,
    const float* __restrict__ W1, const float* __restrict__ b1,
    float* __restrict__ PiP, float* __restrict__ PjTP, float* __restrict__ Gc)
{
    const int blk = blockIdx.x;
    const int tid = threadIdx.x;

    if (blk >= 2 * NROWBLK) {
        // ---- Gc block: one per b ----
        __shared__ float red[256];
        const int b = blk - 2 * NROWBLK;
        const int h = tid & 127, part = tid >> 7;
        const float* g = gctx + b * ND + part * 64;
        const float* w = W1 + (size_t)(6 * ND + NREL + part * 64) * NH + h;
        float acc = 0.f;
#pragma unroll 8
        for (int d = 0; d < 64; ++d) acc += g[d] * w[d * NH];
        red[tid] = acc;
        __syncthreads();
        if (part == 0) Gc[b * NH + h] = red[h] + red[h + 128] + b1[h];
        return;
    }

    const int rb = blk >> 1;
    const int kh = blk & 1;              // which half of k = 0..383
    const int r0 = rb * ROWS;

    __shared__ __align__(16) float X[ROWS][192];

    // stage 6 rows x 192 k's of [coord|goal|frontier]
    for (int idx = tid; idx < ROWS * 192; idx += 256) {
        int r = idx / 192;
        int kk = idx - r * 192;
        int k = kh * 192 + kk;
        int s = k >> 7, d = k & 127;
        const float* src = (s == 0) ? coord : (s == 1) ? goal : frontier;
        X[r][kk] = src[(r0 + r) * ND + d];
    }
    __syncthreads();

    const int colLocal = tid & 127;
    const int role = tid >> 7;           // 0 = i-role, 1 = j-role
    const int roleOff = role * 128;

    float acc[ROWS];
#pragma unroll
    for (int r = 0; r < ROWS; r++) acc[r] = 0.f;

    auto seg = [&](int kkStart, int sChunk, int dStart, int len) {
        const float* wb = W1 + (size_t)(sChunk * 256 + roleOff + dStart) * NH + colLocal;
#pragma unroll 4
        for (int t = 0; t < len; t += 4) {
            float w0 = wb[0 * NH];
            float w1 = wb[1 * NH];
            float w2 = wb[2 * NH];
            float w3 = wb[3 * NH];
            wb += 4 * NH;
#pragma unroll
            for (int r = 0; r < ROWS; r++) {
                float4 x = *(const float4*)&X[r][kkStart + t];
                acc[r] += x.x * w0 + x.y * w1 + x.z * w2 + x.w * w3;
            }
        }
    };
    if (kh == 0) { seg(0, 0, 0, 128); seg(128, 1, 0, 64); }
    else         { seg(0, 1, 64, 64); seg(64, 2, 0, 128); }

#pragma unroll
    for (int r = 0; r < ROWS; r++) {
        int row = r0 + r;
        if (role == 0) {
            PiP[((size_t)kh * NB * NA + row) * NH + colLocal] = acc[r];
        } else {
            int b = row / NA, a = row - b * NA;
            PjTP[(((size_t)kh * NB + b) * NH + colLocal) * NA + a] = acc[r];
        }
    }
}

// ---------------- Kernel 2: per-(b,i) edge MLP + masked softmax ----------------
// 192 threads, lane = j. Combines the two k-half partials on the fly.
__global__ __launch_bounds__(192) void edge_kernel(
    const float* __restrict__ PiP, const float* __restrict__ PjTP,
    const float* __restrict__ Gc, const float* __restrict__ W1,
    const float* __restrict__ W2, const float* __restrict__ b2v,
    const float* __restrict__ rel_feat, const int* __restrict__ rule_adj,
    const float* __restrict__ base_score,
    float* __restrict__ out_w, float* __restrict__ out_s, float* __restrict__ out_l)
{
    const int bi = blockIdx.x;           // b*NA + i
    const int b = bi / NA;
    const int tid = threadIdx.x;         // = j, 0..191

    __shared__ float4 su1[NH];           // {pig, wrel0, wrel1, wrel2}
    __shared__ float4 su2[NH];           // {wrel3, wrel4, w2, 0}
    __shared__ float redA[3], redB[3], redC[3];

    if (tid < NH) {
        float pig = PiP[(size_t)bi * NH + tid]
                  + PiP[(size_t)(NB * NA + bi) * NH + tid]
                  + Gc[b * NH + tid];
        const float* wr = W1 + (size_t)(6 * ND) * NH + tid;
        su1[tid] = make_float4(pig, wr[0 * NH], wr[1 * NH], wr[2 * NH]);
        su2[tid] = make_float4(wr[3 * NH], wr[4 * NH], W2[tid], 0.f);
    }

    float rel[NREL];
    const float* rf = rel_feat + ((size_t)bi * NA + tid) * NREL;
#pragma unroll
    for (int r = 0; r < NREL; r++) rel[r] = rf[r];

    __syncthreads();

    const float* pj0 = PjTP + (size_t)b * NH * NA + tid;
    const float* pj1 = pj0 + (size_t)NB * NH * NA;
    float acc = 0.f;
#pragma unroll 8
    for (int h = 0; h < NH; ++h) {
        float p = pj0[h * NA] + pj1[h * NA];
        float4 a = su1[h];
        float4 c = su2[h];
        float pre = a.x + p;
        pre += rel[0] * a.y;
        pre += rel[1] * a.z;
        pre += rel[2] * a.w;
        pre += rel[3] * c.x;
        pre += rel[4] * c.y;
        acc += fmaxf(pre, 0.f) * c.z;
    }
    float learned = acc + b2v[0];
    out_l[(size_t)bi * NA + tid] = learned;

    const int adj = rule_adj[(size_t)bi * NA + tid];
    const float sc = adj ? (base_score[(size_t)bi * NA + tid] + learned) : -1e9f;
    out_s[(size_t)bi * NA + tid] = sc;

    const int wave = tid >> 6, lane = tid & 63;

    // max over 192 lanes
    float m = sc;
#pragma unroll
    for (int off = 32; off > 0; off >>= 1) m = fmaxf(m, __shfl_xor(m, off, 64));
    if (lane == 0) redA[wave] = m;
    __syncthreads();
    m = fmaxf(fmaxf(redA[0], redA[1]), redA[2]);

    // sum of exp
    float e = __expf(sc - m);
    float S = e;
#pragma unroll
    for (int off = 32; off > 0; off >>= 1) S += __shfl_xor(S, off, 64);
    if (lane == 0) redB[wave] = S;
    __syncthreads();
    S = redB[0] + redB[1] + redB[2];

    // masked renorm
    float wj = adj ? e * (1.f / S) : 0.f;
    float sw = wj;
#pragma unroll
    for (int off = 32; off > 0; off >>= 1) sw += __shfl_xor(sw, off, 64);
    if (lane == 0) redC[wave] = sw;
    __syncthreads();
    sw = redC[0] + redC[1] + redC[2];

    out_w[(size_t)bi * NA + tid] = wj * (1.f / (sw + 1e-8f));
}

extern "C" void kernel_launch(void* const* d_in, const int* in_sizes, int n_in,
                              void* d_out, int out_size, void* d_ws, size_t ws_size,
                              hipStream_t stream) {
    const float* coord    = (const float*)d_in[0];
    const float* goal     = (const float*)d_in[1];
    const float* frontier = (const float*)d_in[2];
    const float* rel_feat = (const float*)d_in[3];
    const int*   rule_adj = (const int*)d_in[4];
    const float* base_sc  = (const float*)d_in[5];
    const float* gctx     = (const float*)d_in[6];
    const float* W1       = (const float*)d_in[7];
    const float* b1       = (const float*)d_in[8];
    const float* W2       = (const float*)d_in[9];
    const float* b2       = (const float*)d_in[10];

    float* PiP  = (float*)d_ws;                   // 2 * 1536 * 128 floats
    float* PjTP = PiP + 2 * NB * NA * NH;         // 2 * 8 * 128 * 192 floats
    float* Gc   = PjTP + 2 * NB * NH * NA;        // 8 * 128

    float* out_w = (float*)d_out;
    float* out_s = out_w + NB * NA * NA;
    float* out_l = out_s + NB * NA * NA;

    precompute_P<<<2 * NROWBLK + NB, 256, 0, stream>>>(coord, goal, frontier, gctx,
                                                       W1, b1, PiP, PjTP, Gc);
    edge_kernel<<<NB * NA, 192, 0, stream>>>(PiP, PjTP, Gc, W1, W2, b2, rel_feat,
                                             rule_adj, base_sc, out_w, out_s, out_l);
}